// Round 1
// baseline (23538.947 us; speedup 1.0000x reference)
//
#include <hip/hip_runtime.h>
#include <math.h>

// ---------------------------------------------------------------------------
// UAVEnhancedModel: LSTM-with-decay + per-step LayerNorm recurrence (S=4096,
// I=512, H=1024) + uav feature path + sigmoid head.
//
// Structure:
//   1) gemm_xp: x_proj = x @ W_ih^T + (b_ih + b_hh)          [4096 x 4096]
//   2) gemm_uf: uf = relu(uav*W1^T + b1) @ W2^T + b2          [4096 x 1024]
//   3) scan:   persistent 256-block kernel; block b owns hidden units
//      4b..4b+3 (16 W_hh rows, 64 weights/thread in VGPRs). One global
//      barrier per step (per-step arrival counter). Cross-block h exchange
//      via agent-scope atomics (coherent across XCD L2s). LayerNorm folded
//      into the matvec via precomputed row sums A_r = sum W*ln_g,
//      B_r = sum W*ln_b:  W @ h_ln = rstd*(dot(W*g, hn) - mu*A_r) + B_r.
//   4) final:  out[t] = sigmoid(ufcW @ h_ln_t + ufcb) from stored hn history;
//      also h_last. (c_last written by scan.)
// ---------------------------------------------------------------------------

constexpr int kS  = 4096;
constexpr int kI  = 512;
constexpr int kH  = 1024;
constexpr int kG4 = 4096;   // 4*kH
constexpr int kNB = 256;    // scan blocks (1 per CU; tiny LDS -> co-resident)
constexpr float kLnEps = 1e-5f;
constexpr float kWdEps = 1e-7f;

__device__ __forceinline__ float sigm(float x) { return 1.f / (1.f + expf(-x)); }

// ---------------- init: zero the per-step arrival counters ----------------
__global__ __launch_bounds__(256) void zero_bar_kernel(int* __restrict__ bar) {
  int i = blockIdx.x * 256 + threadIdx.x;
  if (i < kS) bar[i] = 0;
}

// ---------------- GEMM1: xp[s,r] = sum_k x[s,k]*W_ih[r,k] + bias[r] -------
__global__ __launch_bounds__(256) void gemm_xp_kernel(
    const float* __restrict__ A,     // x [4096,512] row-major
    const float* __restrict__ B,     // W_ih [4096,512] row-major
    const float* __restrict__ b_ih, const float* __restrict__ b_hh,
    float* __restrict__ C)           // xp [4096,4096]
{
  __shared__ float As[32][68];       // [BK][BM+4], 272B row stride (16B-aligned)
  __shared__ float Bs[32][68];
  const int bm = blockIdx.x * 64, bn = blockIdx.y * 64;
  const int tid = threadIdx.x;
  const int tx = tid & 15, ty = tid >> 4;
  float acc[4][4] = {};
  for (int k0 = 0; k0 < kI; k0 += 32) {
#pragma unroll
    for (int h = 0; h < 2; ++h) {
      const int f = tid + h * 256;           // 0..511 -> 512 float4 slots
      const int row = f >> 3, c4 = (f & 7) * 4;
      const float4 a  = *(const float4*)(A + (size_t)(bm + row) * kI + k0 + c4);
      const float4 bb = *(const float4*)(B + (size_t)(bn + row) * kI + k0 + c4);
      As[c4 + 0][row] = a.x;  As[c4 + 1][row] = a.y;
      As[c4 + 2][row] = a.z;  As[c4 + 3][row] = a.w;
      Bs[c4 + 0][row] = bb.x; Bs[c4 + 1][row] = bb.y;
      Bs[c4 + 2][row] = bb.z; Bs[c4 + 3][row] = bb.w;
    }
    __syncthreads();
#pragma unroll
    for (int k = 0; k < 32; ++k) {
      const float4 a  = *(const float4*)&As[k][ty * 4];
      const float4 bb = *(const float4*)&Bs[k][tx * 4];
      const float av[4] = {a.x, a.y, a.z, a.w};
      const float bv[4] = {bb.x, bb.y, bb.z, bb.w};
#pragma unroll
      for (int i = 0; i < 4; ++i)
#pragma unroll
        for (int j = 0; j < 4; ++j) acc[i][j] += av[i] * bv[j];
    }
    __syncthreads();
  }
  const float4 bi = *(const float4*)(b_ih + bn + tx * 4);
  const float4 bh = *(const float4*)(b_hh + bn + tx * 4);
  const float4 bias = make_float4(bi.x + bh.x, bi.y + bh.y, bi.z + bh.z, bi.w + bh.w);
#pragma unroll
  for (int i = 0; i < 4; ++i) {
    float4 o = make_float4(acc[i][0] + bias.x, acc[i][1] + bias.y,
                           acc[i][2] + bias.z, acc[i][3] + bias.w);
    *(float4*)(C + (size_t)(bm + ty * 4 + i) * kG4 + bn + tx * 4) = o;
  }
}

// ---------------- GEMM2: uf[s,h2] = sum_k relu(uav[s]*W1[k]+b1[k])*W2[h2,k] + b2[h2]
__global__ __launch_bounds__(256) void gemm_uf_kernel(
    const float* __restrict__ uav,   // [4096]
    const float* __restrict__ W1, const float* __restrict__ b1,  // [1024]
    const float* __restrict__ W2,    // [1024,1024] row-major
    const float* __restrict__ b2,    // [1024]
    float* __restrict__ C)           // uf [4096,1024]
{
  __shared__ float As[32][68];
  __shared__ float Bs[32][68];
  __shared__ float uav_s[64];
  const int bm = blockIdx.x * 64, bn = blockIdx.y * 64;
  const int tid = threadIdx.x;
  const int tx = tid & 15, ty = tid >> 4;
  if (tid < 64) uav_s[tid] = uav[bm + tid];
  __syncthreads();
  float acc[4][4] = {};
  for (int k0 = 0; k0 < kH; k0 += 32) {
#pragma unroll
    for (int h = 0; h < 2; ++h) {
      const int f = tid + h * 256;
      const int row = f >> 3, c4 = (f & 7) * 4;
      const float4 w1v = *(const float4*)(W1 + k0 + c4);
      const float4 b1v = *(const float4*)(b1 + k0 + c4);
      const float ua = uav_s[row];
      As[c4 + 0][row] = fmaxf(ua * w1v.x + b1v.x, 0.f);
      As[c4 + 1][row] = fmaxf(ua * w1v.y + b1v.y, 0.f);
      As[c4 + 2][row] = fmaxf(ua * w1v.z + b1v.z, 0.f);
      As[c4 + 3][row] = fmaxf(ua * w1v.w + b1v.w, 0.f);
      const float4 bb = *(const float4*)(W2 + (size_t)(bn + row) * kH + k0 + c4);
      Bs[c4 + 0][row] = bb.x; Bs[c4 + 1][row] = bb.y;
      Bs[c4 + 2][row] = bb.z; Bs[c4 + 3][row] = bb.w;
    }
    __syncthreads();
#pragma unroll
    for (int k = 0; k < 32; ++k) {
      const float4 a  = *(const float4*)&As[k][ty * 4];
      const float4 bb = *(const float4*)&Bs[k][tx * 4];
      const float av[4] = {a.x, a.y, a.z, a.w};
      const float bv[4] = {bb.x, bb.y, bb.z, bb.w};
#pragma unroll
      for (int i = 0; i < 4; ++i)
#pragma unroll
        for (int j = 0; j < 4; ++j) acc[i][j] += av[i] * bv[j];
    }
    __syncthreads();
  }
  const float4 b2v = *(const float4*)(b2 + bn + tx * 4);
#pragma unroll
  for (int i = 0; i < 4; ++i) {
    float4 o = make_float4(acc[i][0] + b2v.x, acc[i][1] + b2v.y,
                           acc[i][2] + b2v.z, acc[i][3] + b2v.w);
    *(float4*)(C + (size_t)(bm + ty * 4 + i) * kH + bn + tx * 4) = o;
  }
}

// ---------------- persistent scan kernel ----------------
// 256 blocks x 256 threads. Block b owns units j0=4b..4b+3 (16 gate rows).
// Thread (lr = tid>>4, idx = tid&15) holds 64 weights of row
// grow = (lr>>2)*H + j0 + (lr&3): w[4*mm+e] = W_hh[grow][idx*4 + mm*64 + e].
__global__ __launch_bounds__(256) void scan_kernel(
    const float* __restrict__ xp,     // [S,4H] ws
    const float* __restrict__ uf,     // [S,H]  ws
    float* hn,                        // [S,H]  ws (agent-scope atomics)
    int* bar,                         // [S]    ws arrival counters
    const float* __restrict__ W_hh,   // [4H,H]
    const float* __restrict__ deltas, // [S]
    const float* __restrict__ Wd,     // [H]
    const float* __restrict__ ln_g,   // [H]
    const float* __restrict__ ln_b,   // [H]
    float* __restrict__ out)          // d_out (c_last slice)
{
  const int b = blockIdx.x;
  const int tid = threadIdx.x;
  const int j0 = b * 4;
  const int lr = tid >> 4, idx = tid & 15;
  const int grow = (lr >> 2) * kH + j0 + (lr & 3);

  __shared__ float hn_l[kH];
  __shared__ float Ar[16], Br[16], gate_s[16], xp_s[16];
  __shared__ float red1[4], red2[4], muv[2];

  // --- load this thread's 64 W_hh weights into registers (raw) ---
  float w[64];
#pragma unroll
  for (int mm = 0; mm < 16; ++mm) {
    const float4 wv = *(const float4*)(W_hh + (size_t)grow * kH + idx * 4 + mm * 64);
    w[4 * mm + 0] = wv.x; w[4 * mm + 1] = wv.y;
    w[4 * mm + 2] = wv.z; w[4 * mm + 3] = wv.w;
  }
  const float4 g4 = *(const float4*)(ln_g + 4 * tid);
  const float4 b4 = *(const float4*)(ln_b + 4 * tid);

  // --- Br = sum_j W[grow][j]*ln_b[j] (dot with raw w) ---
  *(float4*)&hn_l[4 * tid] = b4;
  __syncthreads();
  {
    float acc = 0.f;
#pragma unroll
    for (int mm = 0; mm < 16; ++mm) {
      const float4 h4 = *(const float4*)&hn_l[idx * 4 + mm * 64];
      acc += w[4 * mm + 0] * h4.x + w[4 * mm + 1] * h4.y +
             w[4 * mm + 2] * h4.z + w[4 * mm + 3] * h4.w;
    }
#pragma unroll
    for (int d = 1; d < 16; d <<= 1) acc += __shfl_xor(acc, d, 64);
    if (idx == 0) Br[lr] = acc;
  }
  __syncthreads();
  // --- scale w by ln_g; Ar = sum of scaled row ---
  *(float4*)&hn_l[4 * tid] = g4;
  __syncthreads();
  {
    float acc = 0.f;
#pragma unroll
    for (int mm = 0; mm < 16; ++mm) {
      const float4 h4 = *(const float4*)&hn_l[idx * 4 + mm * 64];
      w[4 * mm + 0] *= h4.x; w[4 * mm + 1] *= h4.y;
      w[4 * mm + 2] *= h4.z; w[4 * mm + 3] *= h4.w;
      acc += w[4 * mm + 0] + w[4 * mm + 1] + w[4 * mm + 2] + w[4 * mm + 3];
    }
#pragma unroll
    for (int d = 1; d < 16; d <<= 1) acc += __shfl_xor(acc, d, 64);
    if (idx == 0) Ar[lr] = acc;
  }
  __syncthreads();

  float c_state = 0.f, wdc = 0.f;
  if (tid < 4) wdc = fminf(fmaxf(Wd[j0 + tid], kWdEps), 10.f);

  for (int t = 0; t < kS; ++t) {
    // prefetch streamed (constant) operands; latency hides under spin/gather
    float xp_r = 0.f, uf_r = 0.f, dl = 0.f;
    if (tid < 16) xp_r = xp[(size_t)t * kG4 + (tid >> 2) * kH + j0 + (tid & 3)];
    if (tid < 4) { uf_r = uf[(size_t)t * kH + j0 + tid]; dl = deltas[t]; }

    if (t > 0) {
      if (tid == 0) {
        while (__hip_atomic_load(&bar[t - 1], __ATOMIC_RELAXED,
                                 __HIP_MEMORY_SCOPE_AGENT) < kNB)
          __builtin_amdgcn_s_sleep(1);
      }
      __syncthreads();
      // gather full hn[t-1] (coherent agent-scope loads) + LN stats
      float* hp = hn + (size_t)(t - 1) * kH + 4 * tid;
      const float v0 = __hip_atomic_load(hp + 0, __ATOMIC_RELAXED, __HIP_MEMORY_SCOPE_AGENT);
      const float v1 = __hip_atomic_load(hp + 1, __ATOMIC_RELAXED, __HIP_MEMORY_SCOPE_AGENT);
      const float v2 = __hip_atomic_load(hp + 2, __ATOMIC_RELAXED, __HIP_MEMORY_SCOPE_AGENT);
      const float v3 = __hip_atomic_load(hp + 3, __ATOMIC_RELAXED, __HIP_MEMORY_SCOPE_AGENT);
      *(float4*)&hn_l[4 * tid] = make_float4(v0, v1, v2, v3);
      float s1 = v0 + v1 + v2 + v3;
      float s2 = v0 * v0 + v1 * v1 + v2 * v2 + v3 * v3;
#pragma unroll
      for (int d = 1; d < 64; d <<= 1) {
        s1 += __shfl_xor(s1, d, 64);
        s2 += __shfl_xor(s2, d, 64);
      }
      if ((tid & 63) == 0) { red1[tid >> 6] = s1; red2[tid >> 6] = s2; }
      __syncthreads();
      if (tid == 0) {
        const float S1 = red1[0] + red1[1] + red1[2] + red1[3];
        const float S2 = red2[0] + red2[1] + red2[2] + red2[3];
        const float mu = S1 * (1.f / kH);
        const float var = S2 * (1.f / kH) - mu * mu;
        muv[0] = mu; muv[1] = 1.f / sqrtf(var + kLnEps);
      }
      __syncthreads();
      const float mu = muv[0], rstd = muv[1];
      // matvec: dot(W*g, hn_prev) for this thread's row slice
      float acc = 0.f;
#pragma unroll
      for (int mm = 0; mm < 16; ++mm) {
        const float4 h4 = *(const float4*)&hn_l[idx * 4 + mm * 64];
        acc += w[4 * mm + 0] * h4.x + w[4 * mm + 1] * h4.y +
               w[4 * mm + 2] * h4.z + w[4 * mm + 3] * h4.w;
      }
#pragma unroll
      for (int d = 1; d < 16; d <<= 1) acc += __shfl_xor(acc, d, 64);
      if (idx == 0) gate_s[lr] = rstd * (acc - mu * Ar[lr]) + Br[lr];
    }
    if (tid < 16) xp_s[tid] = xp_r;
    __syncthreads();

    if (tid < 4) {
      const float gi_ = xp_s[0 + tid]  + ((t > 0) ? gate_s[0 + tid]  : 0.f);
      const float gf_ = xp_s[4 + tid]  + ((t > 0) ? gate_s[4 + tid]  : 0.f);
      const float gg_ = xp_s[8 + tid]  + ((t > 0) ? gate_s[8 + tid]  : 0.f);
      const float go_ = xp_s[12 + tid] + ((t > 0) ? gate_s[12 + tid] : 0.f);
      const float dec = expf(-dl * wdc);
      const float cn_u = sigm(gf_) * (c_state * dec) + sigm(gi_) * tanhf(gg_);
      float hv = sigm(go_) * tanhf(cn_u) + 1.5f * uf_r;   // tanh of UNclipped c (matches ref)
      hv = fminf(fmaxf(hv, -10.f), 10.f);
      c_state = fminf(fmaxf(cn_u, -10.f), 10.f);
      __hip_atomic_store(hn + (size_t)t * kH + j0 + tid, hv,
                         __ATOMIC_RELAXED, __HIP_MEMORY_SCOPE_AGENT);
    }
    // drain the coherent stores to the LLC before signaling arrival
    asm volatile("s_waitcnt vmcnt(0)" ::: "memory");
    __syncthreads();
    if (tid == 0)
      __hip_atomic_fetch_add(&bar[t], 1, __ATOMIC_RELAXED, __HIP_MEMORY_SCOPE_AGENT);
  }
  if (tid < 4) out[kS + kH + j0 + tid] = c_state;   // c_last
}

// ---------------- final pass: out[t], h_last ----------------
__global__ __launch_bounds__(256) void final_kernel(
    const float* __restrict__ hn, const float* __restrict__ ufcW,
    const float* __restrict__ ufcb, const float* __restrict__ ln_g,
    const float* __restrict__ ln_b, float* __restrict__ out)
{
  const int t = blockIdx.x, tid = threadIdx.x;
  __shared__ float red[4][5];
  __shared__ float muv[2];
  const float4 hv = *(const float4*)(hn + (size_t)t * kH + 4 * tid);
  const float4 uw = *(const float4*)(ufcW + 4 * tid);
  const float4 g4 = *(const float4*)(ln_g + 4 * tid);
  const float4 b4 = *(const float4*)(ln_b + 4 * tid);
  float s1 = hv.x + hv.y + hv.z + hv.w;
  float s2 = hv.x * hv.x + hv.y * hv.y + hv.z * hv.z + hv.w * hv.w;
  float p  = uw.x * g4.x * hv.x + uw.y * g4.y * hv.y + uw.z * g4.z * hv.z + uw.w * g4.w * hv.w;
  float uu = uw.x * g4.x + uw.y * g4.y + uw.z * g4.z + uw.w * g4.w;
  float cc = uw.x * b4.x + uw.y * b4.y + uw.z * b4.z + uw.w * b4.w;
#pragma unroll
  for (int d = 1; d < 64; d <<= 1) {
    s1 += __shfl_xor(s1, d, 64); s2 += __shfl_xor(s2, d, 64);
    p  += __shfl_xor(p, d, 64);  uu += __shfl_xor(uu, d, 64);
    cc += __shfl_xor(cc, d, 64);
  }
  if ((tid & 63) == 0) {
    const int wv = tid >> 6;
    red[wv][0] = s1; red[wv][1] = s2; red[wv][2] = p; red[wv][3] = uu; red[wv][4] = cc;
  }
  __syncthreads();
  if (tid == 0) {
    float S1 = 0, S2 = 0, P = 0, U = 0, C = 0;
    for (int wv = 0; wv < 4; ++wv) {
      S1 += red[wv][0]; S2 += red[wv][1]; P += red[wv][2];
      U += red[wv][3];  C += red[wv][4];
    }
    const float mu = S1 * (1.f / kH);
    const float var = S2 * (1.f / kH) - mu * mu;
    const float rstd = 1.f / sqrtf(var + kLnEps);
    const float val = rstd * (P - mu * U) + C + ufcb[0];
    out[t] = 1.f / (1.f + expf(-val));
    muv[0] = mu; muv[1] = rstd;
  }
  if (t == kS - 1) {   // h_last = h_ln of final step
    __syncthreads();
    const float mu = muv[0], rstd = muv[1];
    out[kS + 4 * tid + 0] = (hv.x - mu) * rstd * g4.x + b4.x;
    out[kS + 4 * tid + 1] = (hv.y - mu) * rstd * g4.y + b4.y;
    out[kS + 4 * tid + 2] = (hv.z - mu) * rstd * g4.z + b4.z;
    out[kS + 4 * tid + 3] = (hv.w - mu) * rstd * g4.w + b4.w;
  }
}

// ---------------- launch ----------------
extern "C" void kernel_launch(void* const* d_in, const int* in_sizes, int n_in,
                              void* d_out, int out_size, void* d_ws, size_t ws_size,
                              hipStream_t stream) {
  (void)in_sizes; (void)n_in; (void)out_size; (void)ws_size;
  const float* x      = (const float*)d_in[0];
  const float* deltas = (const float*)d_in[1];
  const float* uavf   = (const float*)d_in[2];
  const float* W_ih   = (const float*)d_in[3];
  const float* W_hh   = (const float*)d_in[4];
  const float* b_ih   = (const float*)d_in[5];
  const float* b_hh   = (const float*)d_in[6];
  const float* Wd     = (const float*)d_in[7];
  const float* uavW1  = (const float*)d_in[8];
  const float* uavb1  = (const float*)d_in[9];
  const float* uavW2  = (const float*)d_in[10];
  const float* uavb2  = (const float*)d_in[11];
  const float* ufcW   = (const float*)d_in[12];
  const float* ufcb   = (const float*)d_in[13];
  const float* ln_g   = (const float*)d_in[14];
  const float* ln_b   = (const float*)d_in[15];
  float* out = (float*)d_out;

  // ws layout (floats): xp 16777216 | uf 4194304 | hn 4194304 | bar (ints) 4096
  float* ws = (float*)d_ws;
  float* xp = ws;
  float* uf = ws + 16777216;
  float* hn = ws + 20971520;
  int*  bar = (int*)(ws + 25165824);

  zero_bar_kernel<<<16, 256, 0, stream>>>(bar);
  gemm_xp_kernel<<<dim3(64, 64), 256, 0, stream>>>(x, W_ih, b_ih, b_hh, xp);
  gemm_uf_kernel<<<dim3(64, 16), 256, 0, stream>>>(uavf, uavW1, uavb1, uavW2, uavb2, uf);
  scan_kernel<<<kNB, 256, 0, stream>>>(xp, uf, hn, bar, W_hh, deltas, Wd, ln_g, ln_b, out);
  final_kernel<<<kS, 256, 0, stream>>>(hn, ufcW, ufcb, ln_g, ln_b, out);
}

// Round 2
// 14727.722 us; speedup vs baseline: 1.5983x; 1.5983x over previous
//
#include <hip/hip_runtime.h>
#include <math.h>

// ---------------------------------------------------------------------------
// UAVEnhancedModel: LSTM-with-decay + per-step LayerNorm recurrence (S=4096,
// I=512, H=1024) + uav feature path + sigmoid head.
//
//   1) gemm_xp: x_proj = x @ W_ih^T + (b_ih + b_hh)          [4096 x 4096]
//   2) gemm_uf: uf = relu(uav*W1^T + b1) @ W2^T + b2          [4096 x 1024]
//   3) scan:   persistent 256-block kernel; block b owns hidden units
//      4b..4b+3 (16 W_hh rows, 64 weights/thread in VGPRs).
//      Cross-block sync is DATA-FLOW: hn[] is pre-filled with a sentinel
//      (1e30); producers store h via agent-scope atomics, consumers poll
//      their own 4 words until != sentinel. No counters, no contention.
//      LayerNorm folded into the matvec via precomputed row sums
//      A_r = sum W*ln_g, B_r = sum W*ln_b:
//        W @ h_ln = rstd*(dot(W*g, hn) - mu*A_r) + B_r.
//   4) final:  out[t] = sigmoid(ufcW @ h_ln_t + ufcb); also h_last, c_last.
// ---------------------------------------------------------------------------

constexpr int kS  = 4096;
constexpr int kI  = 512;
constexpr int kH  = 1024;
constexpr int kG4 = 4096;   // 4*kH
constexpr int kNB = 256;    // scan blocks (1 per CU; co-resident)
constexpr float kLnEps = 1e-5f;
constexpr float kWdEps = 1e-7f;
constexpr float kSent  = 1e30f;   // h is clipped to [-10,10] -> unreachable

__device__ __forceinline__ float sigm(float x) { return 1.f / (1.f + expf(-x)); }

// ---------------- init: fill hn with sentinel ----------------
__global__ __launch_bounds__(256) void init_hn_kernel(float4* __restrict__ p) {
  const int i = blockIdx.x * 256 + threadIdx.x;   // 4096*256 float4 = S*H floats
  p[i] = make_float4(kSent, kSent, kSent, kSent);
}

// ---------------- GEMM1: xp[s,r] = sum_k x[s,k]*W_ih[r,k] + bias[r] -------
__global__ __launch_bounds__(256) void gemm_xp_kernel(
    const float* __restrict__ A,     // x [4096,512] row-major
    const float* __restrict__ B,     // W_ih [4096,512] row-major
    const float* __restrict__ b_ih, const float* __restrict__ b_hh,
    float* __restrict__ C)           // xp [4096,4096]
{
  __shared__ float As[32][68];
  __shared__ float Bs[32][68];
  const int bm = blockIdx.x * 64, bn = blockIdx.y * 64;
  const int tid = threadIdx.x;
  const int tx = tid & 15, ty = tid >> 4;
  float acc[4][4] = {};
  for (int k0 = 0; k0 < kI; k0 += 32) {
#pragma unroll
    for (int h = 0; h < 2; ++h) {
      const int f = tid + h * 256;
      const int row = f >> 3, c4 = (f & 7) * 4;
      const float4 a  = *(const float4*)(A + (size_t)(bm + row) * kI + k0 + c4);
      const float4 bb = *(const float4*)(B + (size_t)(bn + row) * kI + k0 + c4);
      As[c4 + 0][row] = a.x;  As[c4 + 1][row] = a.y;
      As[c4 + 2][row] = a.z;  As[c4 + 3][row] = a.w;
      Bs[c4 + 0][row] = bb.x; Bs[c4 + 1][row] = bb.y;
      Bs[c4 + 2][row] = bb.z; Bs[c4 + 3][row] = bb.w;
    }
    __syncthreads();
#pragma unroll
    for (int k = 0; k < 32; ++k) {
      const float4 a  = *(const float4*)&As[k][ty * 4];
      const float4 bb = *(const float4*)&Bs[k][tx * 4];
      const float av[4] = {a.x, a.y, a.z, a.w};
      const float bv[4] = {bb.x, bb.y, bb.z, bb.w};
#pragma unroll
      for (int i = 0; i < 4; ++i)
#pragma unroll
        for (int j = 0; j < 4; ++j) acc[i][j] += av[i] * bv[j];
    }
    __syncthreads();
  }
  const float4 bi = *(const float4*)(b_ih + bn + tx * 4);
  const float4 bh = *(const float4*)(b_hh + bn + tx * 4);
  const float4 bias = make_float4(bi.x + bh.x, bi.y + bh.y, bi.z + bh.z, bi.w + bh.w);
#pragma unroll
  for (int i = 0; i < 4; ++i) {
    float4 o = make_float4(acc[i][0] + bias.x, acc[i][1] + bias.y,
                           acc[i][2] + bias.z, acc[i][3] + bias.w);
    *(float4*)(C + (size_t)(bm + ty * 4 + i) * kG4 + bn + tx * 4) = o;
  }
}

// ---------------- GEMM2: uf = relu(uav*W1^T + b1) @ W2^T + b2 ----------------
__global__ __launch_bounds__(256) void gemm_uf_kernel(
    const float* __restrict__ uav,
    const float* __restrict__ W1, const float* __restrict__ b1,
    const float* __restrict__ W2,
    const float* __restrict__ b2,
    float* __restrict__ C)           // uf [4096,1024]
{
  __shared__ float As[32][68];
  __shared__ float Bs[32][68];
  __shared__ float uav_s[64];
  const int bm = blockIdx.x * 64, bn = blockIdx.y * 64;
  const int tid = threadIdx.x;
  const int tx = tid & 15, ty = tid >> 4;
  if (tid < 64) uav_s[tid] = uav[bm + tid];
  __syncthreads();
  float acc[4][4] = {};
  for (int k0 = 0; k0 < kH; k0 += 32) {
#pragma unroll
    for (int h = 0; h < 2; ++h) {
      const int f = tid + h * 256;
      const int row = f >> 3, c4 = (f & 7) * 4;
      const float4 w1v = *(const float4*)(W1 + k0 + c4);
      const float4 b1v = *(const float4*)(b1 + k0 + c4);
      const float ua = uav_s[row];
      As[c4 + 0][row] = fmaxf(ua * w1v.x + b1v.x, 0.f);
      As[c4 + 1][row] = fmaxf(ua * w1v.y + b1v.y, 0.f);
      As[c4 + 2][row] = fmaxf(ua * w1v.z + b1v.z, 0.f);
      As[c4 + 3][row] = fmaxf(ua * w1v.w + b1v.w, 0.f);
      const float4 bb = *(const float4*)(W2 + (size_t)(bn + row) * kH + k0 + c4);
      Bs[c4 + 0][row] = bb.x; Bs[c4 + 1][row] = bb.y;
      Bs[c4 + 2][row] = bb.z; Bs[c4 + 3][row] = bb.w;
    }
    __syncthreads();
#pragma unroll
    for (int k = 0; k < 32; ++k) {
      const float4 a  = *(const float4*)&As[k][ty * 4];
      const float4 bb = *(const float4*)&Bs[k][tx * 4];
      const float av[4] = {a.x, a.y, a.z, a.w};
      const float bv[4] = {bb.x, bb.y, bb.z, bb.w};
#pragma unroll
      for (int i = 0; i < 4; ++i)
#pragma unroll
        for (int j = 0; j < 4; ++j) acc[i][j] += av[i] * bv[j];
    }
    __syncthreads();
  }
  const float4 b2v = *(const float4*)(b2 + bn + tx * 4);
#pragma unroll
  for (int i = 0; i < 4; ++i) {
    float4 o = make_float4(acc[i][0] + b2v.x, acc[i][1] + b2v.y,
                           acc[i][2] + b2v.z, acc[i][3] + b2v.w);
    *(float4*)(C + (size_t)(bm + ty * 4 + i) * kH + bn + tx * 4) = o;
  }
}

// ---------------- persistent scan kernel ----------------
// 256 blocks x 256 threads. Block b owns units j0=4b..4b+3 (16 gate rows).
// Thread (lr = tid>>4, idx = tid&15) holds 64 weights of row
// grow = (lr>>2)*H + j0 + (lr&3): w[4*mm+e] = W_hh[grow][idx*4 + mm*64 + e].
// Sync: data-flow via sentinel polling on hn (agent-scope atomics).
__global__ __launch_bounds__(256) void scan_kernel(
    const float* __restrict__ xp,     // [S,4H] ws
    const float* __restrict__ uf,     // [S,H]  ws
    float* hn,                        // [S,H]  ws (sentinel-initialized)
    const float* __restrict__ W_hh,   // [4H,H]
    const float* __restrict__ deltas, // [S]
    const float* __restrict__ Wd,     // [H]
    const float* __restrict__ ln_g,   // [H]
    const float* __restrict__ ln_b,   // [H]
    float* __restrict__ out)          // d_out (c_last slice)
{
  const int b = blockIdx.x;
  const int tid = threadIdx.x;
  const int j0 = b * 4;
  const int lr = tid >> 4, idx = tid & 15;
  const int grow = (lr >> 2) * kH + j0 + (lr & 3);

  __shared__ float hn_l[kH];
  __shared__ float Ar[16], Br[16], gate_s[16], xp_s[16];
  __shared__ float red1[4], red2[4];

  // --- load this thread's 64 W_hh weights into registers (raw) ---
  float w[64];
#pragma unroll
  for (int mm = 0; mm < 16; ++mm) {
    const float4 wv = *(const float4*)(W_hh + (size_t)grow * kH + idx * 4 + mm * 64);
    w[4 * mm + 0] = wv.x; w[4 * mm + 1] = wv.y;
    w[4 * mm + 2] = wv.z; w[4 * mm + 3] = wv.w;
  }
  const float4 g4 = *(const float4*)(ln_g + 4 * tid);
  const float4 b4 = *(const float4*)(ln_b + 4 * tid);

  // --- Br = dot(W_row, ln_b) ---
  *(float4*)&hn_l[4 * tid] = b4;
  __syncthreads();
  {
    float acc = 0.f;
#pragma unroll
    for (int mm = 0; mm < 16; ++mm) {
      const float4 h4 = *(const float4*)&hn_l[idx * 4 + mm * 64];
      acc += w[4 * mm + 0] * h4.x + w[4 * mm + 1] * h4.y +
             w[4 * mm + 2] * h4.z + w[4 * mm + 3] * h4.w;
    }
#pragma unroll
    for (int d = 1; d < 16; d <<= 1) acc += __shfl_xor(acc, d, 64);
    if (idx == 0) Br[lr] = acc;
  }
  __syncthreads();
  // --- scale w by ln_g; Ar = row sum of scaled weights ---
  *(float4*)&hn_l[4 * tid] = g4;
  __syncthreads();
  {
    float acc = 0.f;
#pragma unroll
    for (int mm = 0; mm < 16; ++mm) {
      const float4 h4 = *(const float4*)&hn_l[idx * 4 + mm * 64];
      w[4 * mm + 0] *= h4.x; w[4 * mm + 1] *= h4.y;
      w[4 * mm + 2] *= h4.z; w[4 * mm + 3] *= h4.w;
      acc += w[4 * mm + 0] + w[4 * mm + 1] + w[4 * mm + 2] + w[4 * mm + 3];
    }
#pragma unroll
    for (int d = 1; d < 16; d <<= 1) acc += __shfl_xor(acc, d, 64);
    if (idx == 0) Ar[lr] = acc;
  }
  __syncthreads();

  float c_state = 0.f, wdc = 0.f;
  if (tid < 4) wdc = fminf(fmaxf(Wd[j0 + tid], kWdEps), 10.f);

  for (int t = 0; t < kS; ++t) {
    // prefetch streamed operands; latency hides under poll/gather
    float xp_r = 0.f, uf_r = 0.f, dl = 0.f;
    if (tid < 16) xp_r = xp[(size_t)t * kG4 + (tid >> 2) * kH + j0 + (tid & 3)];
    if (tid < 4) { uf_r = uf[(size_t)t * kH + j0 + tid]; dl = deltas[t]; }

    if (t > 0) {
      // ---- data-flow gather: poll own 4 words of hn[t-1] until real ----
      float* hp = hn + (size_t)(t - 1) * kH + 4 * tid;
      float v0 = __hip_atomic_load(hp + 0, __ATOMIC_RELAXED, __HIP_MEMORY_SCOPE_AGENT);
      float v1 = __hip_atomic_load(hp + 1, __ATOMIC_RELAXED, __HIP_MEMORY_SCOPE_AGENT);
      float v2 = __hip_atomic_load(hp + 2, __ATOMIC_RELAXED, __HIP_MEMORY_SCOPE_AGENT);
      float v3 = __hip_atomic_load(hp + 3, __ATOMIC_RELAXED, __HIP_MEMORY_SCOPE_AGENT);
      while (v0 == kSent || v1 == kSent || v2 == kSent || v3 == kSent) {
        v0 = __hip_atomic_load(hp + 0, __ATOMIC_RELAXED, __HIP_MEMORY_SCOPE_AGENT);
        v1 = __hip_atomic_load(hp + 1, __ATOMIC_RELAXED, __HIP_MEMORY_SCOPE_AGENT);
        v2 = __hip_atomic_load(hp + 2, __ATOMIC_RELAXED, __HIP_MEMORY_SCOPE_AGENT);
        v3 = __hip_atomic_load(hp + 3, __ATOMIC_RELAXED, __HIP_MEMORY_SCOPE_AGENT);
      }
      *(float4*)&hn_l[4 * tid] = make_float4(v0, v1, v2, v3);
      // LN stats partials (wave-level)
      float s1 = v0 + v1 + v2 + v3;
      float s2 = v0 * v0 + v1 * v1 + v2 * v2 + v3 * v3;
#pragma unroll
      for (int d = 1; d < 64; d <<= 1) {
        s1 += __shfl_xor(s1, d, 64);
        s2 += __shfl_xor(s2, d, 64);
      }
      if ((tid & 63) == 0) { red1[tid >> 6] = s1; red2[tid >> 6] = s2; }
      if (tid < 16) xp_s[tid] = xp_r;
      __syncthreads();   // hn_l + red + xp_s visible
      // every thread combines partials redundantly (LDS broadcast reads)
      const float S1 = red1[0] + red1[1] + red1[2] + red1[3];
      const float S2 = red2[0] + red2[1] + red2[2] + red2[3];
      const float mu = S1 * (1.f / kH);
      const float var = S2 * (1.f / kH) - mu * mu;
      const float rstd = 1.f / sqrtf(var + kLnEps);
      // matvec: dot(W*g, hn_prev) for this thread's row slice
      float acc = 0.f;
#pragma unroll
      for (int mm = 0; mm < 16; ++mm) {
        const float4 h4 = *(const float4*)&hn_l[idx * 4 + mm * 64];
        acc += w[4 * mm + 0] * h4.x + w[4 * mm + 1] * h4.y +
               w[4 * mm + 2] * h4.z + w[4 * mm + 3] * h4.w;
      }
#pragma unroll
      for (int d = 1; d < 16; d <<= 1) acc += __shfl_xor(acc, d, 64);
      if (idx == 0) gate_s[lr] = rstd * (acc - mu * Ar[lr]) + Br[lr];
      __syncthreads();
    } else {
      if (tid < 16) xp_s[tid] = xp_r;
      __syncthreads();
    }

    if (tid < 4) {
      const float gi_ = xp_s[0 + tid]  + ((t > 0) ? gate_s[0 + tid]  : 0.f);
      const float gf_ = xp_s[4 + tid]  + ((t > 0) ? gate_s[4 + tid]  : 0.f);
      const float gg_ = xp_s[8 + tid]  + ((t > 0) ? gate_s[8 + tid]  : 0.f);
      const float go_ = xp_s[12 + tid] + ((t > 0) ? gate_s[12 + tid] : 0.f);
      const float dec = expf(-dl * wdc);
      const float cn_u = sigm(gf_) * (c_state * dec) + sigm(gi_) * tanhf(gg_);
      float hv = sigm(go_) * tanhf(cn_u) + 1.5f * uf_r;   // tanh of UNclipped c
      hv = fminf(fmaxf(hv, -10.f), 10.f);
      // publish ASAP: consumers poll this word directly
      __hip_atomic_store(hn + (size_t)t * kH + j0 + tid, hv,
                         __ATOMIC_RELAXED, __HIP_MEMORY_SCOPE_AGENT);
      c_state = fminf(fmaxf(cn_u, -10.f), 10.f);
    }
    __syncthreads();   // protect hn_l/gate_s/xp_s for next iteration
  }
  if (tid < 4) out[kS + kH + j0 + tid] = c_state;   // c_last
}

// ---------------- final pass: out[t], h_last ----------------
__global__ __launch_bounds__(256) void final_kernel(
    const float* __restrict__ hn, const float* __restrict__ ufcW,
    const float* __restrict__ ufcb, const float* __restrict__ ln_g,
    const float* __restrict__ ln_b, float* __restrict__ out)
{
  const int t = blockIdx.x, tid = threadIdx.x;
  __shared__ float red[4][5];
  __shared__ float muv[2];
  const float4 hv = *(const float4*)(hn + (size_t)t * kH + 4 * tid);
  const float4 uw = *(const float4*)(ufcW + 4 * tid);
  const float4 g4 = *(const float4*)(ln_g + 4 * tid);
  const float4 b4 = *(const float4*)(ln_b + 4 * tid);
  float s1 = hv.x + hv.y + hv.z + hv.w;
  float s2 = hv.x * hv.x + hv.y * hv.y + hv.z * hv.z + hv.w * hv.w;
  float p  = uw.x * g4.x * hv.x + uw.y * g4.y * hv.y + uw.z * g4.z * hv.z + uw.w * g4.w * hv.w;
  float uu = uw.x * g4.x + uw.y * g4.y + uw.z * g4.z + uw.w * g4.w;
  float cc = uw.x * b4.x + uw.y * b4.y + uw.z * b4.z + uw.w * b4.w;
#pragma unroll
  for (int d = 1; d < 64; d <<= 1) {
    s1 += __shfl_xor(s1, d, 64); s2 += __shfl_xor(s2, d, 64);
    p  += __shfl_xor(p, d, 64);  uu += __shfl_xor(uu, d, 64);
    cc += __shfl_xor(cc, d, 64);
  }
  if ((tid & 63) == 0) {
    const int wv = tid >> 6;
    red[wv][0] = s1; red[wv][1] = s2; red[wv][2] = p; red[wv][3] = uu; red[wv][4] = cc;
  }
  __syncthreads();
  if (tid == 0) {
    float S1 = 0, S2 = 0, P = 0, U = 0, C = 0;
    for (int wv = 0; wv < 4; ++wv) {
      S1 += red[wv][0]; S2 += red[wv][1]; P += red[wv][2];
      U += red[wv][3];  C += red[wv][4];
    }
    const float mu = S1 * (1.f / kH);
    const float var = S2 * (1.f / kH) - mu * mu;
    const float rstd = 1.f / sqrtf(var + kLnEps);
    const float val = rstd * (P - mu * U) + C + ufcb[0];
    out[t] = 1.f / (1.f + expf(-val));
    muv[0] = mu; muv[1] = rstd;
  }
  if (t == kS - 1) {   // h_last = h_ln of final step
    __syncthreads();
    const float mu = muv[0], rstd = muv[1];
    out[kS + 4 * tid + 0] = (hv.x - mu) * rstd * g4.x + b4.x;
    out[kS + 4 * tid + 1] = (hv.y - mu) * rstd * g4.y + b4.y;
    out[kS + 4 * tid + 2] = (hv.z - mu) * rstd * g4.z + b4.z;
    out[kS + 4 * tid + 3] = (hv.w - mu) * rstd * g4.w + b4.w;
  }
}

// ---------------- launch ----------------
extern "C" void kernel_launch(void* const* d_in, const int* in_sizes, int n_in,
                              void* d_out, int out_size, void* d_ws, size_t ws_size,
                              hipStream_t stream) {
  (void)in_sizes; (void)n_in; (void)out_size; (void)ws_size;
  const float* x      = (const float*)d_in[0];
  const float* deltas = (const float*)d_in[1];
  const float* uavf   = (const float*)d_in[2];
  const float* W_ih   = (const float*)d_in[3];
  const float* W_hh   = (const float*)d_in[4];
  const float* b_ih   = (const float*)d_in[5];
  const float* b_hh   = (const float*)d_in[6];
  const float* Wd     = (const float*)d_in[7];
  const float* uavW1  = (const float*)d_in[8];
  const float* uavb1  = (const float*)d_in[9];
  const float* uavW2  = (const float*)d_in[10];
  const float* uavb2  = (const float*)d_in[11];
  const float* ufcW   = (const float*)d_in[12];
  const float* ufcb   = (const float*)d_in[13];
  const float* ln_g   = (const float*)d_in[14];
  const float* ln_b   = (const float*)d_in[15];
  float* out = (float*)d_out;

  // ws layout (floats): xp 16777216 | uf 4194304 | hn 4194304
  float* ws = (float*)d_ws;
  float* xp = ws;
  float* uf = ws + 16777216;
  float* hn = ws + 20971520;

  init_hn_kernel<<<4096, 256, 0, stream>>>((float4*)hn);
  gemm_xp_kernel<<<dim3(64, 64), 256, 0, stream>>>(x, W_ih, b_ih, b_hh, xp);
  gemm_uf_kernel<<<dim3(64, 16), 256, 0, stream>>>(uavf, uavW1, uavb1, uavW2, uavb2, uf);
  scan_kernel<<<kNB, 256, 0, stream>>>(xp, uf, hn, W_hh, deltas, Wd, ln_g, ln_b, out);
  final_kernel<<<kS, 256, 0, stream>>>(hn, ufcW, ufcb, ln_g, ln_b, out);
}